// Round 6
// baseline (12903.526 us; speedup 1.0000x reference)
//
#include <hip/hip_runtime.h>
#include <math.h>

// ---------- wave-wide sum (64 lanes), fixed deterministic order ----------
__device__ __forceinline__ float wred(float s) {
  #pragma unroll
  for (int o = 32; o > 0; o >>= 1) s += __shfl_xor(s, o, 64);
  return s;
}

__device__ __forceinline__ float fma4(float4 w, float4 a, float acc) {
  return fmaf(w.w, a.w, fmaf(w.z, a.z, fmaf(w.y, a.y, fmaf(w.x, a.x, acc))));
}

// ==================== TR=32 helpers (k_table only, cold path) ====================
__device__ __forceinline__ void ln_rows32(float (*A)[256], const float* __restrict__ gg,
                                          const float* __restrict__ bb, int t) {
  const int w = t >> 6, l = t & 63;
  const float g0 = gg[l], g1 = gg[l + 64], g2 = gg[l + 128], g3 = gg[l + 192];
  const float c0 = bb[l], c1 = bb[l + 64], c2 = bb[l + 128], c3 = bb[l + 192];
  #pragma unroll
  for (int rr = 0; rr < 8; ++rr) {
    const int r = w * 8 + rr;
    const float v0 = A[r][l], v1 = A[r][l + 64], v2 = A[r][l + 128], v3 = A[r][l + 192];
    float s = ((v0 + v1) + v2) + v3;
    s = wred(s);
    const float mu = s * (1.f / 256.f);
    const float d0 = v0 - mu, d1 = v1 - mu, d2 = v2 - mu, d3 = v3 - mu;
    float s2 = fmaf(d3, d3, fmaf(d2, d2, fmaf(d1, d1, d0 * d0)));
    s2 = wred(s2);
    const float var = s2 * (1.f / 256.f);
    const float rs = 1.f / sqrtf(var + 1e-5f);
    A[r][l]       = (d0 * rs) * g0 + c0;
    A[r][l + 64]  = (d1 * rs) * g1 + c1;
    A[r][l + 128] = (d2 * rs) * g2 + c2;
    A[r][l + 192] = (d3 * rs) * g3 + c3;
  }
  __syncthreads();
}

__device__ __forceinline__ void hidden_layer32(float (*A)[256], const float* __restrict__ W,
                                               const float* __restrict__ B, int t) {
  const int g = t >> 7;
  const int j0 = t & 127, j1 = j0 + 128;
  const float4* W0 = (const float4*)(W + j0 * 256);
  const float4* W1 = (const float4*)(W + j1 * 256);
  float acc0[16], acc1[16];
  #pragma unroll
  for (int r = 0; r < 16; ++r) { acc0[r] = 0.f; acc1[r] = 0.f; }
  #pragma unroll 2
  for (int kq = 0; kq < 64; ++kq) {
    const float4 wq0 = W0[kq], wq1 = W1[kq];
    #pragma unroll
    for (int rr = 0; rr < 16; ++rr) {
      const float4 a = *(const float4*)&A[g * 16 + rr][kq * 4];
      acc0[rr] = fma4(wq0, a, acc0[rr]);
      acc1[rr] = fma4(wq1, a, acc1[rr]);
    }
  }
  const float bb0 = B[j0], bb1 = B[j1];
  __syncthreads();
  #pragma unroll
  for (int rr = 0; rr < 16; ++rr) {
    const int r = g * 16 + rr;
    A[r][j0] = fmaxf(acc0[rr] + bb0, 0.f);
    A[r][j1] = fmaxf(acc1[rr] + bb1, 0.f);
  }
  __syncthreads();
}

// ==================== k_enc: 128 threads (2 col-split waves), 16 rows ====================
// A[16][256] activations; P[16][34]: cols 0..31 partials, 32 = mu, 33 = rs.

__device__ __forceinline__ void ldw2x4(float2* wv, const float* __restrict__ WT, int kq, int cw) {
  #pragma unroll
  for (int k = 0; k < 4; ++k) wv[k] = *(const float2*)&WT[(kq * 4 + k) * 256 + cw];
}
__device__ __forceinline__ void lda4(float4* a, const float (*A)[256], int rb, int kq) {
  #pragma unroll
  for (int i = 0; i < 4; ++i) a[i] = *(const float4*)&A[rb + i][kq * 4];
}
__device__ __forceinline__ void fma4r(const float4* a, int rb, const float2* wv, float2* acc) {
  #pragma unroll
  for (int i = 0; i < 4; ++i) {
    const float4 av = a[i];
    float2 o = acc[rb + i];
    o.x = fmaf(av.x, wv[0].x, o.x); o.y = fmaf(av.x, wv[0].y, o.y);
    o.x = fmaf(av.y, wv[1].x, o.x); o.y = fmaf(av.y, wv[1].y, o.y);
    o.x = fmaf(av.z, wv[2].x, o.x); o.y = fmaf(av.z, wv[2].y, o.y);
    o.x = fmaf(av.w, wv[3].x, o.x); o.y = fmaf(av.w, wv[3].y, o.y);
    acc[rb + i] = o;
  }
}

// hidden layer: acc = relu(A @ WT + B); A in LDS; W ping-pong + 4-row A-batch ping-pong
__device__ __forceinline__ void hid128(const float (*A)[256], const float* __restrict__ WT,
                                       const float* __restrict__ Bp, int cw, float2* acc) {
  #pragma unroll
  for (int r = 0; r < 16; ++r) acc[r] = make_float2(0.f, 0.f);
  float2 wc[4], wn[4];
  float4 aA[4], aB[4];
  ldw2x4(wc, WT, 0, cw);
  lda4(aA, A, 0, 0);
  #pragma unroll 1
  for (int kq = 0; kq < 64; kq += 2) {
    ldw2x4(wn, WT, kq + 1, cw);
    lda4(aB, A, 4, kq);
    fma4r(aA, 0, wc, acc);
    lda4(aA, A, 8, kq);
    fma4r(aB, 4, wc, acc);
    lda4(aB, A, 12, kq);
    fma4r(aA, 8, wc, acc);
    lda4(aA, A, 0, kq + 1);
    fma4r(aB, 12, wc, acc);
    if (kq + 2 < 64) ldw2x4(wc, WT, kq + 2, cw);
    lda4(aB, A, 4, kq + 1);
    fma4r(aA, 0, wn, acc);
    lda4(aA, A, 8, kq + 1);
    fma4r(aB, 4, wn, acc);
    lda4(aB, A, 12, kq + 1);
    fma4r(aA, 8, wn, acc);
    if (kq + 2 < 64) lda4(aA, A, 0, kq + 2);
    fma4r(aB, 12, wn, acc);
  }
  const float2 bb = *(const float2*)&Bp[cw];
  #pragma unroll
  for (int r = 0; r < 16; ++r) {
    acc[r].x = fmaxf(acc[r].x + bb.x, 0.f);
    acc[r].y = fmaxf(acc[r].y + bb.y, 0.f);
  }
}

// LayerNorm, centered two-pass (reference shape). 2-col lanes, 2 waves.
__device__ __forceinline__ void ln128(float2* acc, float (*P)[34],
                                      const float* __restrict__ gg,
                                      const float* __restrict__ bb,
                                      int l, int w, int cw) {
  float p[16];
  // ---- pass 1: mean ----
  #pragma unroll
  for (int r = 0; r < 16; ++r) p[r] = acc[r].x + acc[r].y;
  #pragma unroll
  for (int r = 0; r < 16; ++r) p[r] += __shfl_xor(p[r], 32, 64);
  #pragma unroll
  for (int r = 0; r < 16; ++r) p[r] += __shfl_xor(p[r], 16, 64);
  __syncthreads();                       // prior P consumers done
  if (l < 16) {
    #pragma unroll
    for (int r = 0; r < 16; ++r) P[r][w * 16 + l] = p[r];
  }
  __syncthreads();
  if (w == 0 && l < 16) {
    float q[8];
    #pragma unroll
    for (int j = 0; j < 8; ++j) {
      const float4 u = *(const float4*)&P[l][4 * j];
      q[j] = (u.x + u.y) + (u.z + u.w);
    }
    const float s = ((q[0] + q[1]) + (q[2] + q[3])) + ((q[4] + q[5]) + (q[6] + q[7]));
    P[l][32] = s * (1.f / 256.f);
  }
  __syncthreads();
  // ---- pass 2: centered variance ----
  #pragma unroll
  for (int r = 0; r < 16; ++r) {
    const float mu = P[r][32];           // broadcast read
    const float dx = acc[r].x - mu, dy = acc[r].y - mu;
    p[r] = fmaf(dy, dy, dx * dx);
  }
  #pragma unroll
  for (int r = 0; r < 16; ++r) p[r] += __shfl_xor(p[r], 32, 64);
  #pragma unroll
  for (int r = 0; r < 16; ++r) p[r] += __shfl_xor(p[r], 16, 64);
  if (l < 16) {
    #pragma unroll
    for (int r = 0; r < 16; ++r) P[r][w * 16 + l] = p[r];   // slots 0..31 (!= 32) - no race
  }
  __syncthreads();
  if (w == 0 && l < 16) {
    float q[8];
    #pragma unroll
    for (int j = 0; j < 8; ++j) {
      const float4 u = *(const float4*)&P[l][4 * j];
      q[j] = (u.x + u.y) + (u.z + u.w);
    }
    const float s2 = ((q[0] + q[1]) + (q[2] + q[3])) + ((q[4] + q[5]) + (q[6] + q[7]));
    const float var = s2 * (1.f / 256.f);
    P[l][33] = 1.f / sqrtf(var + 1e-5f);
  }
  __syncthreads();
  // ---- normalize in registers: ((x-mu)*rs)*g + b ----
  const float2 g = *(const float2*)&gg[cw];
  const float2 c = *(const float2*)&bb[cw];
  #pragma unroll
  for (int r = 0; r < 16; ++r) {
    const float2 st = *(const float2*)&P[r][32];
    const float2 v = acc[r];
    acc[r].x = ((v.x - st.x) * st.y) * g.x + c.x;
    acc[r].y = ((v.y - st.x) * st.y) * g.y + c.y;
  }
}

__device__ __forceinline__ void storeA128(float (*A)[256], const float2* acc, int cw) {
  #pragma unroll
  for (int r = 0; r < 16; ++r) *(float2*)&A[r][cw] = acc[r];
}

// out layer 256 -> 64: wave w rows w*8..+7, lane = 1 output col
__device__ __forceinline__ void out128(const float (*A)[256], const float* __restrict__ WTo,
                                       const float* __restrict__ bo, float* __restrict__ zout,
                                       int l, int w) {
  const int r0 = w * 8;
  float o[8];
  #pragma unroll
  for (int rr = 0; rr < 8; ++rr) o[rr] = 0.f;
  #pragma unroll 2
  for (int kq = 0; kq < 64; ++kq) {
    const float w0v = WTo[(kq * 4 + 0) * 64 + l];
    const float w1v = WTo[(kq * 4 + 1) * 64 + l];
    const float w2v = WTo[(kq * 4 + 2) * 64 + l];
    const float w3v = WTo[(kq * 4 + 3) * 64 + l];
    #pragma unroll
    for (int rr = 0; rr < 8; ++rr) {
      const float4 a = *(const float4*)&A[r0 + rr][kq * 4];
      o[rr] = fmaf(a.w, w3v, fmaf(a.z, w2v, fmaf(a.y, w1v, fmaf(a.x, w0v, o[rr]))));
    }
  }
  const float bb = bo[l];
  #pragma unroll
  for (int rr = 0; rr < 8; ++rr) zout[(r0 + rr) * 64 + l] = o[rr] + bb;
}

__global__ __launch_bounds__(128, 4) void k_enc(
    const float* __restrict__ x, const float* __restrict__ w0,
    const float* __restrict__ b0, const float* __restrict__ wt1,
    const float* __restrict__ wt2, const float* __restrict__ bh,
    const float* __restrict__ lng, const float* __restrict__ lnb,
    const float* __restrict__ wtout, const float* __restrict__ bout,
    float* __restrict__ z) {
  __shared__ float A[16][256];
  __shared__ float P[16][34];
  const int t = threadIdx.x;
  const int l = t & 63;
  const int w = t >> 6;
  const int cw = w * 128 + l * 2;
  const size_t rbase = (size_t)blockIdx.x * 16;
  float2 acc[16];

  { // layer 0: 3 -> 256 (x reads wave-uniform -> scalar loads)
    const float wa0 = w0[cw * 3 + 0], wa1 = w0[cw * 3 + 1], wa2 = w0[cw * 3 + 2];
    const float wb0 = w0[cw * 3 + 3], wb1 = w0[cw * 3 + 4], wb2 = w0[cw * 3 + 5];
    const float2 bb = *(const float2*)&b0[cw];
    #pragma unroll
    for (int r = 0; r < 16; ++r) {
      const float x0 = x[(rbase + r) * 3];
      const float x1 = x[(rbase + r) * 3 + 1];
      const float x2 = x[(rbase + r) * 3 + 2];
      acc[r].x = fmaxf(fmaf(wa2, x2, fmaf(wa1, x1, wa0 * x0)) + bb.x, 0.f);
      acc[r].y = fmaxf(fmaf(wb2, x2, fmaf(wb1, x1, wb0 * x0)) + bb.y, 0.f);
    }
  }
  ln128(acc, P, lng, lnb, l, w, cw);
  storeA128(A, acc, cw);
  __syncthreads();

  hid128(A, wt1, bh, cw, acc);
  ln128(acc, P, lng + 256, lnb + 256, l, w, cw);
  storeA128(A, acc, cw);
  __syncthreads();

  hid128(A, wt2, bh + 256, cw, acc);
  ln128(acc, P, lng + 512, lnb + 512, l, w, cw);
  storeA128(A, acc, cw);
  __syncthreads();

  out128(A, wtout, bout, z + rbase * 64, l, w);
}

// ---------------- weight transpose: WT[k][j] = W[j][k] ----------------
__global__ __launch_bounds__(256) void k_wt(const float* __restrict__ wh,
                                            const float* __restrict__ wout,
                                            float* __restrict__ wt1, float* __restrict__ wt2,
                                            float* __restrict__ wtout) {
  const int b = blockIdx.x, t = threadIdx.x;
  if (b < 256) {
    wt1[b * 256 + t] = wh[t * 256 + b];
  } else if (b < 512) {
    const int k = b - 256;
    wt2[k * 256 + t] = wh[65536 + t * 256 + k];
  } else {
    const int k = (b - 512) * 4 + (t >> 6);
    const int j = t & 63;
    wtout[k * 64 + j] = wout[j * 256 + k];
  }
}

// -------- decode table: table[512][3] = dec(codebook), ne[512] = ||e||^2 --------
__global__ __launch_bounds__(256) void k_table(
    const float* __restrict__ cb, const float* __restrict__ w0,
    const float* __restrict__ b0, const float* __restrict__ wh,
    const float* __restrict__ bh, const float* __restrict__ lng,
    const float* __restrict__ lnb, const float* __restrict__ wout,
    const float* __restrict__ bout, float* __restrict__ table,
    float* __restrict__ ne) {
  __shared__ float A[32][256];
  __shared__ float cs[32][64];
  const int t = threadIdx.x;
  const int cbase = blockIdx.x * 32;
  {
    float4* d = (float4*)&cs[0][0];
    const float4* s = (const float4*)(cb + cbase * 64);
    d[t] = s[t];
    d[t + 256] = s[t + 256];
  }
  __syncthreads();
  if (t < 32) {
    float s = 0.f;
    #pragma unroll 8
    for (int k = 0; k < 64; ++k) s = fmaf(cs[t][k], cs[t][k], s);
    ne[cbase + t] = s;
  }
  {
    const float4* Wr = (const float4*)(w0 + t * 64);
    float acc[32];
    #pragma unroll
    for (int r = 0; r < 32; ++r) acc[r] = 0.f;
    for (int kq = 0; kq < 16; ++kq) {
      const float4 w = Wr[kq];
      #pragma unroll
      for (int r = 0; r < 32; ++r) {
        const float4 a = *(const float4*)&cs[r][kq * 4];
        acc[r] = fma4(w, a, acc[r]);
      }
    }
    const float bb = b0[t];
    #pragma unroll
    for (int r = 0; r < 32; ++r) A[r][t] = fmaxf(acc[r] + bb, 0.f);
  }
  __syncthreads();
  ln_rows32(A, lng, lnb, t);
  hidden_layer32(A, wh, bh, t);
  ln_rows32(A, lng + 256, lnb + 256, t);
  hidden_layer32(A, wh + 65536, bh + 256, t);
  ln_rows32(A, lng + 512, lnb + 512, t);
  if (t < 96) {
    const int r = t / 3, j = t - r * 3;
    const float4* Wr = (const float4*)(wout + j * 256);
    float s = 0.f;
    #pragma unroll 4
    for (int kq = 0; kq < 64; ++kq) {
      const float4 w = Wr[kq];
      const float4 a = *(const float4*)&A[r][kq * 4];
      s = fma4(w, a, s);
    }
    table[(cbase + r) * 3 + j] = s + bout[j];
  }
}

// ---- VQ: z (in zq_io) -> argmin, quantized in-place, recon gather, partials ----
__global__ __launch_bounds__(256) void k_vq(
    float* __restrict__ zq_io, const float* __restrict__ cb,
    const float* __restrict__ ne, const float* __restrict__ table,
    const float* __restrict__ x, float* __restrict__ recon,
    float* __restrict__ psr, float* __restrict__ psv) {
  __shared__ float red[256];
  const int t = threadIdx.x;
  const int row = blockIdx.x * 256 + t;
  float4 zf[16];
  {
    const float4* zp = (const float4*)(zq_io + (size_t)row * 64);
    #pragma unroll
    for (int q = 0; q < 16; ++q) zf[q] = zp[q];
  }
  float nz = 0.f;
  #pragma unroll
  for (int q = 0; q < 16; ++q) {
    nz = fmaf(zf[q].x, zf[q].x, nz);
    nz = fmaf(zf[q].y, zf[q].y, nz);
    nz = fmaf(zf[q].z, zf[q].z, nz);
    nz = fmaf(zf[q].w, zf[q].w, nz);
  }
  float dmin = INFINITY; int imin = 0;
  const float4* cbv = (const float4*)cb;
  for (int c = 0; c < 512; ++c) {
    float da = 0.f, db = 0.f;
    #pragma unroll
    for (int q = 0; q < 16; q += 2) {
      const float4 ea = cbv[c * 16 + q];
      const float4 eb = cbv[c * 16 + q + 1];
      da = fmaf(ea.x, zf[q].x, da);
      da = fmaf(ea.y, zf[q].y, da);
      da = fmaf(ea.z, zf[q].z, da);
      da = fmaf(ea.w, zf[q].w, da);
      db = fmaf(eb.x, zf[q + 1].x, db);
      db = fmaf(eb.y, zf[q + 1].y, db);
      db = fmaf(eb.z, zf[q + 1].z, db);
      db = fmaf(eb.w, zf[q + 1].w, db);
    }
    const float dot = da + db;
    const float d = (nz + ne[c]) - 2.f * dot;
    if (d < dmin) { dmin = d; imin = c; }
  }
  float sv = 0.f;
  {
    const float4* eq = (const float4*)(cb + imin * 64);
    float4* qo = (float4*)(zq_io + (size_t)row * 64);
    #pragma unroll
    for (int q = 0; q < 16; ++q) {
      const float4 e = eq[q];
      const float4 zz = zf[q];
      const float ax = e.x - zz.x, ay = e.y - zz.y, az = e.z - zz.z, aw = e.w - zz.w;
      sv = fmaf(ax, ax, sv); sv = fmaf(ay, ay, sv);
      sv = fmaf(az, az, sv); sv = fmaf(aw, aw, sv);
      float4 st;
      st.x = zz.x + ax; st.y = zz.y + ay; st.z = zz.z + az; st.w = zz.w + aw;
      qo[q] = st;
    }
  }
  const float r0 = table[imin * 3], r1 = table[imin * 3 + 1], r2 = table[imin * 3 + 2];
  recon[row * 3] = r0; recon[row * 3 + 1] = r1; recon[row * 3 + 2] = r2;
  const float e0 = r0 - x[row * 3], e1 = r1 - x[row * 3 + 1], e2 = r2 - x[row * 3 + 2];
  const float sr = fmaf(e2, e2, fmaf(e1, e1, e0 * e0));
  red[t] = sr; __syncthreads();
  #pragma unroll
  for (int o = 128; o > 0; o >>= 1) { if (t < o) red[t] += red[t + o]; __syncthreads(); }
  if (t == 0) psr[blockIdx.x] = red[0];
  __syncthreads();
  red[t] = sv; __syncthreads();
  #pragma unroll
  for (int o = 128; o > 0; o >>= 1) { if (t < o) red[t] += red[t + o]; __syncthreads(); }
  if (t == 0) psv[blockIdx.x] = red[0];
}

// ---------------- final scalar loss ----------------
__global__ __launch_bounds__(256) void k_loss(
    const float* __restrict__ psr, const float* __restrict__ psv,
    float* __restrict__ out) {
  __shared__ float ra[256], rb[256];
  const int t = threadIdx.x;
  const float sr = ((psr[t] + psr[t + 256]) + psr[t + 512]) + psr[t + 768];
  const float sv = ((psv[t] + psv[t + 256]) + psv[t + 512]) + psv[t + 768];
  ra[t] = sr; rb[t] = sv;
  __syncthreads();
  #pragma unroll
  for (int o = 128; o > 0; o >>= 1) {
    if (t < o) { ra[t] += ra[t + o]; rb[t] += rb[t + o]; }
    __syncthreads();
  }
  if (t == 0) {
    const float mr = ra[0] / 786432.f;
    const float mv = rb[0] * (1.f / 16777216.f);
    const float vq = 0.25f * mv + mv;
    out[0] = mr + vq;
  }
}

extern "C" void kernel_launch(void* const* d_in, const int* in_sizes, int n_in,
                              void* d_out, int out_size, void* d_ws, size_t ws_size,
                              hipStream_t stream) {
  const float* x        = (const float*)d_in[0];
  const float* enc_w0   = (const float*)d_in[1];
  const float* enc_b0   = (const float*)d_in[2];
  const float* enc_wh   = (const float*)d_in[3];
  const float* enc_bh   = (const float*)d_in[4];
  const float* enc_lng  = (const float*)d_in[5];
  const float* enc_lnb  = (const float*)d_in[6];
  const float* enc_wout = (const float*)d_in[7];
  const float* enc_bout = (const float*)d_in[8];
  const float* cb       = (const float*)d_in[9];
  const float* dec_w0   = (const float*)d_in[10];
  const float* dec_b0   = (const float*)d_in[11];
  const float* dec_wh   = (const float*)d_in[12];
  const float* dec_bh   = (const float*)d_in[13];
  const float* dec_lng  = (const float*)d_in[14];
  const float* dec_lnb  = (const float*)d_in[15];
  const float* dec_wout = (const float*)d_in[16];
  const float* dec_bout = (const float*)d_in[17];

  float* out   = (float*)d_out;
  float* recon = out;                       // [N,3]
  float* qbuf  = out + 786432;              // [N,64]: z, then quantized in place
  float* lossp = out + 786432 + 16777216;   // scalar

  // Transposed weights live in the recon region (written before k_enc reads them,
  // fully overwritten by k_vq afterwards -> deterministic across replays).
  float* wt1   = out;                       // 65536
  float* wt2   = out + 65536;               // 65536
  float* wtout = out + 131072;              // 16384   (total 147456 < 786432)

  float* ws    = (float*)d_ws;
  float* ne    = ws;          // 512
  float* table = ws + 512;    // 512*3
  float* psr   = ws + 2048;   // 1024
  float* psv   = ws + 3072;   // 1024

  k_wt<<<576, 256, 0, stream>>>(enc_wh, enc_wout, wt1, wt2, wtout);
  k_table<<<16, 256, 0, stream>>>(cb, dec_w0, dec_b0, dec_wh, dec_bh,
                                  dec_lng, dec_lnb, dec_wout, dec_bout,
                                  table, ne);
  k_enc<<<16384, 128, 0, stream>>>(x, enc_w0, enc_b0, wt1, wt2, enc_bh,
                                   enc_lng, enc_lnb, wtout, enc_bout, qbuf);
  k_vq<<<1024, 256, 0, stream>>>(qbuf, cb, ne, table, x, recon, psr, psv);
  k_loss<<<1, 256, 0, stream>>>(psr, psv, lossp);
}

// Round 7
// 1594.205 us; speedup vs baseline: 8.0940x; 8.0940x over previous
//
#include <hip/hip_runtime.h>
#include <math.h>

// ---------- wave-wide sum (64 lanes), fixed deterministic order ----------
__device__ __forceinline__ float wred(float s) {
  #pragma unroll
  for (int o = 32; o > 0; o >>= 1) s += __shfl_xor(s, o, 64);
  return s;
}

__device__ __forceinline__ float fma4(float4 w, float4 a, float acc) {
  return fmaf(w.w, a.w, fmaf(w.z, a.z, fmaf(w.y, a.y, fmaf(w.x, a.x, acc))));
}

// ==================== TR=32 helpers (k_table only, cold path) ====================
__device__ __forceinline__ void ln_rows32(float (*A)[256], const float* __restrict__ gg,
                                          const float* __restrict__ bb, int t) {
  const int w = t >> 6, l = t & 63;
  const float g0 = gg[l], g1 = gg[l + 64], g2 = gg[l + 128], g3 = gg[l + 192];
  const float c0 = bb[l], c1 = bb[l + 64], c2 = bb[l + 128], c3 = bb[l + 192];
  #pragma unroll
  for (int rr = 0; rr < 8; ++rr) {
    const int r = w * 8 + rr;
    const float v0 = A[r][l], v1 = A[r][l + 64], v2 = A[r][l + 128], v3 = A[r][l + 192];
    float s = ((v0 + v1) + v2) + v3;
    s = wred(s);
    const float mu = s * (1.f / 256.f);
    const float d0 = v0 - mu, d1 = v1 - mu, d2 = v2 - mu, d3 = v3 - mu;
    float s2 = fmaf(d3, d3, fmaf(d2, d2, fmaf(d1, d1, d0 * d0)));
    s2 = wred(s2);
    const float var = s2 * (1.f / 256.f);
    const float rs = 1.f / sqrtf(var + 1e-5f);
    A[r][l]       = (d0 * rs) * g0 + c0;
    A[r][l + 64]  = (d1 * rs) * g1 + c1;
    A[r][l + 128] = (d2 * rs) * g2 + c2;
    A[r][l + 192] = (d3 * rs) * g3 + c3;
  }
  __syncthreads();
}

__device__ __forceinline__ void hidden_layer32(float (*A)[256], const float* __restrict__ W,
                                               const float* __restrict__ B, int t) {
  const int g = t >> 7;
  const int j0 = t & 127, j1 = j0 + 128;
  const float4* W0 = (const float4*)(W + j0 * 256);
  const float4* W1 = (const float4*)(W + j1 * 256);
  float acc0[16], acc1[16];
  #pragma unroll
  for (int r = 0; r < 16; ++r) { acc0[r] = 0.f; acc1[r] = 0.f; }
  #pragma unroll 2
  for (int kq = 0; kq < 64; ++kq) {
    const float4 wq0 = W0[kq], wq1 = W1[kq];
    #pragma unroll
    for (int rr = 0; rr < 16; ++rr) {
      const float4 a = *(const float4*)&A[g * 16 + rr][kq * 4];
      acc0[rr] = fma4(wq0, a, acc0[rr]);
      acc1[rr] = fma4(wq1, a, acc1[rr]);
    }
  }
  const float bb0 = B[j0], bb1 = B[j1];
  __syncthreads();
  #pragma unroll
  for (int rr = 0; rr < 16; ++rr) {
    const int r = g * 16 + rr;
    A[r][j0] = fmaxf(acc0[rr] + bb0, 0.f);
    A[r][j1] = fmaxf(acc1[rr] + bb1, 0.f);
  }
  __syncthreads();
}

// ==================== k_enc: 128 threads (2 col-split waves), 16 rows ====================
// A[16][256] activations; P[16][34]: cols 0..31 partials, 32 = mu, 33 = rs.

__device__ __forceinline__ void ldw2x4(float2* wv, const float* __restrict__ WT, int kq, int cw) {
  #pragma unroll
  for (int k = 0; k < 4; ++k) wv[k] = *(const float2*)&WT[(kq * 4 + k) * 256 + cw];
}
__device__ __forceinline__ void lda4(float4* a, const float (*A)[256], int rb, int kq) {
  #pragma unroll
  for (int i = 0; i < 4; ++i) a[i] = *(const float4*)&A[rb + i][kq * 4];
}
__device__ __forceinline__ void fma4r(const float4* a, int rb, const float2* wv, float2* acc) {
  #pragma unroll
  for (int i = 0; i < 4; ++i) {
    const float4 av = a[i];
    float2 o = acc[rb + i];
    o.x = fmaf(av.x, wv[0].x, o.x); o.y = fmaf(av.x, wv[0].y, o.y);
    o.x = fmaf(av.y, wv[1].x, o.x); o.y = fmaf(av.y, wv[1].y, o.y);
    o.x = fmaf(av.z, wv[2].x, o.x); o.y = fmaf(av.z, wv[2].y, o.y);
    o.x = fmaf(av.w, wv[3].x, o.x); o.y = fmaf(av.w, wv[3].y, o.y);
    acc[rb + i] = o;
  }
}

// hidden layer: acc = relu(A @ WT + B); A in LDS; W ping-pong + 4-row A-batch ping-pong
__device__ __forceinline__ void hid128(const float (*A)[256], const float* __restrict__ WT,
                                       const float* __restrict__ Bp, int cw, float2* acc) {
  #pragma unroll
  for (int r = 0; r < 16; ++r) acc[r] = make_float2(0.f, 0.f);
  float2 wc[4], wn[4];
  float4 aA[4], aB[4];
  ldw2x4(wc, WT, 0, cw);
  lda4(aA, A, 0, 0);
  #pragma unroll 1
  for (int kq = 0; kq < 64; kq += 2) {
    ldw2x4(wn, WT, kq + 1, cw);
    lda4(aB, A, 4, kq);
    fma4r(aA, 0, wc, acc);
    lda4(aA, A, 8, kq);
    fma4r(aB, 4, wc, acc);
    lda4(aB, A, 12, kq);
    fma4r(aA, 8, wc, acc);
    lda4(aA, A, 0, kq + 1);
    fma4r(aB, 12, wc, acc);
    if (kq + 2 < 64) ldw2x4(wc, WT, kq + 2, cw);
    lda4(aB, A, 4, kq + 1);
    fma4r(aA, 0, wn, acc);
    lda4(aA, A, 8, kq + 1);
    fma4r(aB, 4, wn, acc);
    lda4(aB, A, 12, kq + 1);
    fma4r(aA, 8, wn, acc);
    if (kq + 2 < 64) lda4(aA, A, 0, kq + 2);
    fma4r(aB, 12, wn, acc);
  }
  const float2 bb = *(const float2*)&Bp[cw];
  #pragma unroll
  for (int r = 0; r < 16; ++r) {
    acc[r].x = fmaxf(acc[r].x + bb.x, 0.f);
    acc[r].y = fmaxf(acc[r].y + bb.y, 0.f);
  }
}

// LayerNorm, centered two-pass (reference shape). 2-col lanes, 2 waves.
__device__ __forceinline__ void ln128(float2* acc, float (*P)[34],
                                      const float* __restrict__ gg,
                                      const float* __restrict__ bb,
                                      int l, int w, int cw) {
  float p[16];
  // ---- pass 1: mean ----
  #pragma unroll
  for (int r = 0; r < 16; ++r) p[r] = acc[r].x + acc[r].y;
  #pragma unroll
  for (int r = 0; r < 16; ++r) p[r] += __shfl_xor(p[r], 32, 64);
  #pragma unroll
  for (int r = 0; r < 16; ++r) p[r] += __shfl_xor(p[r], 16, 64);
  __syncthreads();                       // prior P consumers done
  if (l < 16) {
    #pragma unroll
    for (int r = 0; r < 16; ++r) P[r][w * 16 + l] = p[r];
  }
  __syncthreads();
  if (w == 0 && l < 16) {
    float q[8];
    #pragma unroll
    for (int j = 0; j < 8; ++j) {
      const float4 u = *(const float4*)&P[l][4 * j];
      q[j] = (u.x + u.y) + (u.z + u.w);
    }
    const float s = ((q[0] + q[1]) + (q[2] + q[3])) + ((q[4] + q[5]) + (q[6] + q[7]));
    P[l][32] = s * (1.f / 256.f);
  }
  __syncthreads();
  // ---- pass 2: centered variance ----
  #pragma unroll
  for (int r = 0; r < 16; ++r) {
    const float mu = P[r][32];           // broadcast read
    const float dx = acc[r].x - mu, dy = acc[r].y - mu;
    p[r] = fmaf(dy, dy, dx * dx);
  }
  #pragma unroll
  for (int r = 0; r < 16; ++r) p[r] += __shfl_xor(p[r], 32, 64);
  #pragma unroll
  for (int r = 0; r < 16; ++r) p[r] += __shfl_xor(p[r], 16, 64);
  if (l < 16) {
    #pragma unroll
    for (int r = 0; r < 16; ++r) P[r][w * 16 + l] = p[r];   // slots 0..31 (!= 32) - no race
  }
  __syncthreads();
  if (w == 0 && l < 16) {
    float q[8];
    #pragma unroll
    for (int j = 0; j < 8; ++j) {
      const float4 u = *(const float4*)&P[l][4 * j];
      q[j] = (u.x + u.y) + (u.z + u.w);
    }
    const float s2 = ((q[0] + q[1]) + (q[2] + q[3])) + ((q[4] + q[5]) + (q[6] + q[7]));
    const float var = s2 * (1.f / 256.f);
    P[l][33] = 1.f / sqrtf(var + 1e-5f);
  }
  __syncthreads();
  // ---- normalize in registers: ((x-mu)*rs)*g + b ----
  const float2 g = *(const float2*)&gg[cw];
  const float2 c = *(const float2*)&bb[cw];
  #pragma unroll
  for (int r = 0; r < 16; ++r) {
    const float2 st = *(const float2*)&P[r][32];
    const float2 v = acc[r];
    acc[r].x = ((v.x - st.x) * st.y) * g.x + c.x;
    acc[r].y = ((v.y - st.x) * st.y) * g.y + c.y;
  }
}

__device__ __forceinline__ void storeA128(float (*A)[256], const float2* acc, int cw) {
  #pragma unroll
  for (int r = 0; r < 16; ++r) *(float2*)&A[r][cw] = acc[r];
}

// out layer 256 -> 64: wave w rows w*8..+7, lane = 1 output col
__device__ __forceinline__ void out128(const float (*A)[256], const float* __restrict__ WTo,
                                       const float* __restrict__ bo, float* __restrict__ zout,
                                       int l, int w) {
  const int r0 = w * 8;
  float o[8];
  #pragma unroll
  for (int rr = 0; rr < 8; ++rr) o[rr] = 0.f;
  #pragma unroll 2
  for (int kq = 0; kq < 64; ++kq) {
    const float w0v = WTo[(kq * 4 + 0) * 64 + l];
    const float w1v = WTo[(kq * 4 + 1) * 64 + l];
    const float w2v = WTo[(kq * 4 + 2) * 64 + l];
    const float w3v = WTo[(kq * 4 + 3) * 64 + l];
    #pragma unroll
    for (int rr = 0; rr < 8; ++rr) {
      const float4 a = *(const float4*)&A[r0 + rr][kq * 4];
      o[rr] = fmaf(a.w, w3v, fmaf(a.z, w2v, fmaf(a.y, w1v, fmaf(a.x, w0v, o[rr]))));
    }
  }
  const float bb = bo[l];
  #pragma unroll
  for (int rr = 0; rr < 8; ++rr) zout[(r0 + rr) * 64 + l] = o[rr] + bb;
}

__global__ __launch_bounds__(128, 2) void k_enc(
    const float* __restrict__ x, const float* __restrict__ w0,
    const float* __restrict__ b0, const float* __restrict__ wt1,
    const float* __restrict__ wt2, const float* __restrict__ bh,
    const float* __restrict__ lng, const float* __restrict__ lnb,
    const float* __restrict__ wtout, const float* __restrict__ bout,
    float* __restrict__ z) {
  __shared__ float A[16][256];
  __shared__ float P[16][34];
  const int t = threadIdx.x;
  const int l = t & 63;
  const int w = t >> 6;
  const int cw = w * 128 + l * 2;
  const size_t rbase = (size_t)blockIdx.x * 16;
  float2 acc[16];

  { // layer 0: 3 -> 256 (x reads wave-uniform -> scalar loads)
    const float wa0 = w0[cw * 3 + 0], wa1 = w0[cw * 3 + 1], wa2 = w0[cw * 3 + 2];
    const float wb0 = w0[cw * 3 + 3], wb1 = w0[cw * 3 + 4], wb2 = w0[cw * 3 + 5];
    const float2 bb = *(const float2*)&b0[cw];
    #pragma unroll
    for (int r = 0; r < 16; ++r) {
      const float x0 = x[(rbase + r) * 3];
      const float x1 = x[(rbase + r) * 3 + 1];
      const float x2 = x[(rbase + r) * 3 + 2];
      acc[r].x = fmaxf(fmaf(wa2, x2, fmaf(wa1, x1, wa0 * x0)) + bb.x, 0.f);
      acc[r].y = fmaxf(fmaf(wb2, x2, fmaf(wb1, x1, wb0 * x0)) + bb.y, 0.f);
    }
  }
  ln128(acc, P, lng, lnb, l, w, cw);
  storeA128(A, acc, cw);
  __syncthreads();

  hid128(A, wt1, bh, cw, acc);
  ln128(acc, P, lng + 256, lnb + 256, l, w, cw);
  storeA128(A, acc, cw);
  __syncthreads();

  hid128(A, wt2, bh + 256, cw, acc);
  ln128(acc, P, lng + 512, lnb + 512, l, w, cw);
  storeA128(A, acc, cw);
  __syncthreads();

  out128(A, wtout, bout, z + rbase * 64, l, w);
}

// ---------------- weight transpose: WT[k][j] = W[j][k] ----------------
__global__ __launch_bounds__(256) void k_wt(const float* __restrict__ wh,
                                            const float* __restrict__ wout,
                                            float* __restrict__ wt1, float* __restrict__ wt2,
                                            float* __restrict__ wtout) {
  const int b = blockIdx.x, t = threadIdx.x;
  if (b < 256) {
    wt1[b * 256 + t] = wh[t * 256 + b];
  } else if (b < 512) {
    const int k = b - 256;
    wt2[k * 256 + t] = wh[65536 + t * 256 + k];
  } else {
    const int k = (b - 512) * 4 + (t >> 6);
    const int j = t & 63;
    wtout[k * 64 + j] = wout[j * 256 + k];
  }
}

// -------- decode table: table[512][3] = dec(codebook), ne[512] = ||e||^2 --------
__global__ __launch_bounds__(256) void k_table(
    const float* __restrict__ cb, const float* __restrict__ w0,
    const float* __restrict__ b0, const float* __restrict__ wh,
    const float* __restrict__ bh, const float* __restrict__ lng,
    const float* __restrict__ lnb, const float* __restrict__ wout,
    const float* __restrict__ bout, float* __restrict__ table,
    float* __restrict__ ne) {
  __shared__ float A[32][256];
  __shared__ float cs[32][64];
  const int t = threadIdx.x;
  const int cbase = blockIdx.x * 32;
  {
    float4* d = (float4*)&cs[0][0];
    const float4* s = (const float4*)(cb + cbase * 64);
    d[t] = s[t];
    d[t + 256] = s[t + 256];
  }
  __syncthreads();
  if (t < 32) {
    float s = 0.f;
    #pragma unroll 8
    for (int k = 0; k < 64; ++k) s = fmaf(cs[t][k], cs[t][k], s);
    ne[cbase + t] = s;
  }
  {
    const float4* Wr = (const float4*)(w0 + t * 64);
    float acc[32];
    #pragma unroll
    for (int r = 0; r < 32; ++r) acc[r] = 0.f;
    for (int kq = 0; kq < 16; ++kq) {
      const float4 w = Wr[kq];
      #pragma unroll
      for (int r = 0; r < 32; ++r) {
        const float4 a = *(const float4*)&cs[r][kq * 4];
        acc[r] = fma4(w, a, acc[r]);
      }
    }
    const float bb = b0[t];
    #pragma unroll
    for (int r = 0; r < 32; ++r) A[r][t] = fmaxf(acc[r] + bb, 0.f);
  }
  __syncthreads();
  ln_rows32(A, lng, lnb, t);
  hidden_layer32(A, wh, bh, t);
  ln_rows32(A, lng + 256, lnb + 256, t);
  hidden_layer32(A, wh + 65536, bh + 256, t);
  ln_rows32(A, lng + 512, lnb + 512, t);
  if (t < 96) {
    const int r = t / 3, j = t - r * 3;
    const float4* Wr = (const float4*)(wout + j * 256);
    float s = 0.f;
    #pragma unroll 4
    for (int kq = 0; kq < 64; ++kq) {
      const float4 w = Wr[kq];
      const float4 a = *(const float4*)&A[r][kq * 4];
      s = fma4(w, a, s);
    }
    table[(cbase + r) * 3 + j] = s + bout[j];
  }
}

// ---- VQ: z (in zq_io) -> argmin, quantized in-place, recon gather, partials ----
__global__ __launch_bounds__(256) void k_vq(
    float* __restrict__ zq_io, const float* __restrict__ cb,
    const float* __restrict__ ne, const float* __restrict__ table,
    const float* __restrict__ x, float* __restrict__ recon,
    float* __restrict__ psr, float* __restrict__ psv) {
  __shared__ float red[256];
  const int t = threadIdx.x;
  const int row = blockIdx.x * 256 + t;
  float4 zf[16];
  {
    const float4* zp = (const float4*)(zq_io + (size_t)row * 64);
    #pragma unroll
    for (int q = 0; q < 16; ++q) zf[q] = zp[q];
  }
  float nz = 0.f;
  #pragma unroll
  for (int q = 0; q < 16; ++q) {
    nz = fmaf(zf[q].x, zf[q].x, nz);
    nz = fmaf(zf[q].y, zf[q].y, nz);
    nz = fmaf(zf[q].z, zf[q].z, nz);
    nz = fmaf(zf[q].w, zf[q].w, nz);
  }
  float dmin = INFINITY; int imin = 0;
  const float4* cbv = (const float4*)cb;
  for (int c = 0; c < 512; ++c) {
    float da = 0.f, db = 0.f;
    #pragma unroll
    for (int q = 0; q < 16; q += 2) {
      const float4 ea = cbv[c * 16 + q];
      const float4 eb = cbv[c * 16 + q + 1];
      da = fmaf(ea.x, zf[q].x, da);
      da = fmaf(ea.y, zf[q].y, da);
      da = fmaf(ea.z, zf[q].z, da);
      da = fmaf(ea.w, zf[q].w, da);
      db = fmaf(eb.x, zf[q + 1].x, db);
      db = fmaf(eb.y, zf[q + 1].y, db);
      db = fmaf(eb.z, zf[q + 1].z, db);
      db = fmaf(eb.w, zf[q + 1].w, db);
    }
    const float dot = da + db;
    const float d = (nz + ne[c]) - 2.f * dot;
    if (d < dmin) { dmin = d; imin = c; }
  }
  float sv = 0.f;
  {
    const float4* eq = (const float4*)(cb + imin * 64);
    float4* qo = (float4*)(zq_io + (size_t)row * 64);
    #pragma unroll
    for (int q = 0; q < 16; ++q) {
      const float4 e = eq[q];
      const float4 zz = zf[q];
      const float ax = e.x - zz.x, ay = e.y - zz.y, az = e.z - zz.z, aw = e.w - zz.w;
      sv = fmaf(ax, ax, sv); sv = fmaf(ay, ay, sv);
      sv = fmaf(az, az, sv); sv = fmaf(aw, aw, sv);
      float4 st;
      st.x = zz.x + ax; st.y = zz.y + ay; st.z = zz.z + az; st.w = zz.w + aw;
      qo[q] = st;
    }
  }
  const float r0 = table[imin * 3], r1 = table[imin * 3 + 1], r2 = table[imin * 3 + 2];
  recon[row * 3] = r0; recon[row * 3 + 1] = r1; recon[row * 3 + 2] = r2;
  const float e0 = r0 - x[row * 3], e1 = r1 - x[row * 3 + 1], e2 = r2 - x[row * 3 + 2];
  const float sr = fmaf(e2, e2, fmaf(e1, e1, e0 * e0));
  red[t] = sr; __syncthreads();
  #pragma unroll
  for (int o = 128; o > 0; o >>= 1) { if (t < o) red[t] += red[t + o]; __syncthreads(); }
  if (t == 0) psr[blockIdx.x] = red[0];
  __syncthreads();
  red[t] = sv; __syncthreads();
  #pragma unroll
  for (int o = 128; o > 0; o >>= 1) { if (t < o) red[t] += red[t + o]; __syncthreads(); }
  if (t == 0) psv[blockIdx.x] = red[0];
}

// ---------------- final scalar loss ----------------
__global__ __launch_bounds__(256) void k_loss(
    const float* __restrict__ psr, const float* __restrict__ psv,
    float* __restrict__ out) {
  __shared__ float ra[256], rb[256];
  const int t = threadIdx.x;
  const float sr = ((psr[t] + psr[t + 256]) + psr[t + 512]) + psr[t + 768];
  const float sv = ((psv[t] + psv[t + 256]) + psv[t + 512]) + psv[t + 768];
  ra[t] = sr; rb[t] = sv;
  __syncthreads();
  #pragma unroll
  for (int o = 128; o > 0; o >>= 1) {
    if (t < o) { ra[t] += ra[t + o]; rb[t] += rb[t + o]; }
    __syncthreads();
  }
  if (t == 0) {
    const float mr = ra[0] / 786432.f;
    const float mv = rb[0] * (1.f / 16777216.f);
    const float vq = 0.25f * mv + mv;
    out[0] = mr + vq;
  }
}

extern "C" void kernel_launch(void* const* d_in, const int* in_sizes, int n_in,
                              void* d_out, int out_size, void* d_ws, size_t ws_size,
                              hipStream_t stream) {
  const float* x        = (const float*)d_in[0];
  const float* enc_w0   = (const float*)d_in[1];
  const float* enc_b0   = (const float*)d_in[2];
  const float* enc_wh   = (const float*)d_in[3];
  const float* enc_bh   = (const float*)d_in[4];
  const float* enc_lng  = (const float*)d_in[5];
  const float* enc_lnb  = (const float*)d_in[6];
  const float* enc_wout = (const float*)d_in[7];
  const float* enc_bout = (const float*)d_in[8];
  const float* cb       = (const float*)d_in[9];
  const float* dec_w0   = (const float*)d_in[10];
  const float* dec_b0   = (const float*)d_in[11];
  const float* dec_wh   = (const float*)d_in[12];
  const float* dec_bh   = (const float*)d_in[13];
  const float* dec_lng  = (const float*)d_in[14];
  const float* dec_lnb  = (const float*)d_in[15];
  const float* dec_wout = (const float*)d_in[16];
  const float* dec_bout = (const float*)d_in[17];

  float* out   = (float*)d_out;
  float* recon = out;                       // [N,3]
  float* qbuf  = out + 786432;              // [N,64]: z, then quantized in place
  float* lossp = out + 786432 + 16777216;   // scalar

  // Transposed weights live in the recon region (written before k_enc reads them,
  // fully overwritten by k_vq afterwards -> deterministic across replays).
  float* wt1   = out;                       // 65536
  float* wt2   = out + 65536;               // 65536
  float* wtout = out + 131072;              // 16384   (total 147456 < 786432)

  float* ws    = (float*)d_ws;
  float* ne    = ws;          // 512
  float* table = ws + 512;    // 512*3
  float* psr   = ws + 2048;   // 1024
  float* psv   = ws + 3072;   // 1024

  k_wt<<<576, 256, 0, stream>>>(enc_wh, enc_wout, wt1, wt2, wtout);
  k_table<<<16, 256, 0, stream>>>(cb, dec_w0, dec_b0, dec_wh, dec_bh,
                                  dec_lng, dec_lnb, dec_wout, dec_bout,
                                  table, ne);
  k_enc<<<16384, 128, 0, stream>>>(x, enc_w0, enc_b0, wt1, wt2, enc_bh,
                                   enc_lng, enc_lnb, wtout, enc_bout, qbuf);
  k_vq<<<1024, 256, 0, stream>>>(qbuf, cb, ne, table, x, recon, psr, psv);
  k_loss<<<1, 256, 0, stream>>>(psr, psv, lossp);
}

// Round 8
// 1356.963 us; speedup vs baseline: 9.5091x; 1.1748x over previous
//
#include <hip/hip_runtime.h>
#include <math.h>

// ---------- wave-wide sum (64 lanes), fixed deterministic order ----------
__device__ __forceinline__ float wred(float s) {
  #pragma unroll
  for (int o = 32; o > 0; o >>= 1) s += __shfl_xor(s, o, 64);
  return s;
}

__device__ __forceinline__ float fma4(float4 w, float4 a, float acc) {
  return fmaf(w.w, a.w, fmaf(w.z, a.z, fmaf(w.y, a.y, fmaf(w.x, a.x, acc))));
}

// ==================== TR=32 helpers (k_table only, cold path) ====================
__device__ __forceinline__ void ln_rows32(float (*A)[256], const float* __restrict__ gg,
                                          const float* __restrict__ bb, int t) {
  const int w = t >> 6, l = t & 63;
  const float g0 = gg[l], g1 = gg[l + 64], g2 = gg[l + 128], g3 = gg[l + 192];
  const float c0 = bb[l], c1 = bb[l + 64], c2 = bb[l + 128], c3 = bb[l + 192];
  #pragma unroll
  for (int rr = 0; rr < 8; ++rr) {
    const int r = w * 8 + rr;
    const float v0 = A[r][l], v1 = A[r][l + 64], v2 = A[r][l + 128], v3 = A[r][l + 192];
    float s = ((v0 + v1) + v2) + v3;
    s = wred(s);
    const float mu = s * (1.f / 256.f);
    const float d0 = v0 - mu, d1 = v1 - mu, d2 = v2 - mu, d3 = v3 - mu;
    float s2 = fmaf(d3, d3, fmaf(d2, d2, fmaf(d1, d1, d0 * d0)));
    s2 = wred(s2);
    const float var = s2 * (1.f / 256.f);
    const float rs = 1.f / sqrtf(var + 1e-5f);
    A[r][l]       = (d0 * rs) * g0 + c0;
    A[r][l + 64]  = (d1 * rs) * g1 + c1;
    A[r][l + 128] = (d2 * rs) * g2 + c2;
    A[r][l + 192] = (d3 * rs) * g3 + c3;
  }
  __syncthreads();
}

__device__ __forceinline__ void hidden_layer32(float (*A)[256], const float* __restrict__ W,
                                               const float* __restrict__ B, int t) {
  const int g = t >> 7;
  const int j0 = t & 127, j1 = j0 + 128;
  const float4* W0 = (const float4*)(W + j0 * 256);
  const float4* W1 = (const float4*)(W + j1 * 256);
  float acc0[16], acc1[16];
  #pragma unroll
  for (int r = 0; r < 16; ++r) { acc0[r] = 0.f; acc1[r] = 0.f; }
  #pragma unroll 2
  for (int kq = 0; kq < 64; ++kq) {
    const float4 wq0 = W0[kq], wq1 = W1[kq];
    #pragma unroll
    for (int rr = 0; rr < 16; ++rr) {
      const float4 a = *(const float4*)&A[g * 16 + rr][kq * 4];
      acc0[rr] = fma4(wq0, a, acc0[rr]);
      acc1[rr] = fma4(wq1, a, acc1[rr]);
    }
  }
  const float bb0 = B[j0], bb1 = B[j1];
  __syncthreads();
  #pragma unroll
  for (int rr = 0; rr < 16; ++rr) {
    const int r = g * 16 + rr;
    A[r][j0] = fmaxf(acc0[rr] + bb0, 0.f);
    A[r][j1] = fmaxf(acc1[rr] + bb1, 0.f);
  }
  __syncthreads();
}

// ==================== k_enc: 1 wave, 16 rows, row-group split, 8 cols/lane ====================
// Lane group gr = l>>5 owns rows gr*8..gr*8+7; lane owns cols c0..c0+7 (c0=(l&31)*8).
// A[16][256] activations; P[16][36]: slots 0..31 = partials, 32 = mu/rs.

// LayerNorm, centered two-pass (reference shape), on acc[64] = 8 rows x 8 cols.
__device__ __forceinline__ void ln64g(float* acc, float (*P)[36],
                                      const float* __restrict__ gg,
                                      const float* __restrict__ bb,
                                      int l, int gr8, int c0) {
  const int ls = l & 31;
  float mu[8];
  // ---- pass 1: mean ----
  #pragma unroll
  for (int rr = 0; rr < 8; ++rr) {
    const float* a = &acc[rr * 8];
    const float s = (((a[0] + a[1]) + (a[2] + a[3])) + ((a[4] + a[5]) + (a[6] + a[7])));
    P[gr8 + rr][ls] = s;
  }
  __syncthreads();
  if (l < 16) {
    float q[8];
    #pragma unroll
    for (int j = 0; j < 8; ++j) {
      const float4 u = *(const float4*)&P[l][4 * j];
      q[j] = (u.x + u.y) + (u.z + u.w);
    }
    const float s = ((q[0] + q[1]) + (q[2] + q[3])) + ((q[4] + q[5]) + (q[6] + q[7]));
    P[l][32] = s * (1.f / 256.f);
  }
  __syncthreads();
  #pragma unroll
  for (int rr = 0; rr < 8; ++rr) mu[rr] = P[gr8 + rr][32];   // broadcast
  __syncthreads();
  // ---- pass 2: centered variance ----
  #pragma unroll
  for (int rr = 0; rr < 8; ++rr) {
    const float* a = &acc[rr * 8];
    const float m = mu[rr];
    const float d0 = a[0] - m, d1 = a[1] - m, d2 = a[2] - m, d3 = a[3] - m;
    const float d4 = a[4] - m, d5 = a[5] - m, d6 = a[6] - m, d7 = a[7] - m;
    float s = d0 * d0;
    s = fmaf(d1, d1, s); s = fmaf(d2, d2, s); s = fmaf(d3, d3, s);
    s = fmaf(d4, d4, s); s = fmaf(d5, d5, s); s = fmaf(d6, d6, s); s = fmaf(d7, d7, s);
    P[gr8 + rr][ls] = s;
  }
  __syncthreads();
  if (l < 16) {
    float q[8];
    #pragma unroll
    for (int j = 0; j < 8; ++j) {
      const float4 u = *(const float4*)&P[l][4 * j];
      q[j] = (u.x + u.y) + (u.z + u.w);
    }
    const float s2 = ((q[0] + q[1]) + (q[2] + q[3])) + ((q[4] + q[5]) + (q[6] + q[7]));
    P[l][32] = 1.f / sqrtf(s2 * (1.f / 256.f) + 1e-5f);
  }
  __syncthreads();
  // ---- normalize in registers: ((x-mu)*rs)*g + b ----
  float gv[8], bv[8];
  *(float4*)&gv[0] = *(const float4*)&gg[c0];
  *(float4*)&gv[4] = *(const float4*)&gg[c0 + 4];
  *(float4*)&bv[0] = *(const float4*)&bb[c0];
  *(float4*)&bv[4] = *(const float4*)&bb[c0 + 4];
  #pragma unroll
  for (int rr = 0; rr < 8; ++rr) {
    const float rs = P[gr8 + rr][32];
    const float m = mu[rr];
    #pragma unroll
    for (int c = 0; c < 8; ++c)
      acc[rr * 8 + c] = ((acc[rr * 8 + c] - m) * rs) * gv[c] + bv[c];
  }
  __syncthreads();
}

__device__ __forceinline__ void storeA64g(float (*A)[256], const float* acc, int gr8, int c0) {
  #pragma unroll
  for (int rr = 0; rr < 8; ++rr) {
    *(float4*)&A[gr8 + rr][c0] =
        make_float4(acc[rr * 8], acc[rr * 8 + 1], acc[rr * 8 + 2], acc[rr * 8 + 3]);
    *(float4*)&A[gr8 + rr][c0 + 4] =
        make_float4(acc[rr * 8 + 4], acc[rr * 8 + 5], acc[rr * 8 + 6], acc[rr * 8 + 7]);
  }
}

__global__ __launch_bounds__(64, 2) void k_enc(
    const float* __restrict__ x, const float* __restrict__ w0,
    const float* __restrict__ b0, const float* __restrict__ wt1,
    const float* __restrict__ wt2, const float* __restrict__ bh,
    const float* __restrict__ lng, const float* __restrict__ lnb,
    const float* __restrict__ wtout, const float* __restrict__ bout,
    float* __restrict__ z) {
  __shared__ float A[16][256];
  __shared__ float P[16][36];
  const int l = threadIdx.x;
  const int gr8 = (l >> 5) * 8;        // row group base (0 or 8)
  const int c0 = (l & 31) * 8;         // 8 owned columns
  const size_t rbase = (size_t)blockIdx.x * 16;
  float acc[64];

  { // layer 0: 3 -> 256, 8 rows x 8 cols per lane
    float wv[24], bv[8];
    #pragma unroll
    for (int i = 0; i < 6; ++i) *(float4*)&wv[i * 4] = *(const float4*)&w0[c0 * 3 + i * 4];
    *(float4*)&bv[0] = *(const float4*)&b0[c0];
    *(float4*)&bv[4] = *(const float4*)&b0[c0 + 4];
    #pragma unroll
    for (int rr = 0; rr < 8; ++rr) {
      const size_t r3 = (rbase + gr8 + rr) * 3;
      const float x0 = x[r3], x1 = x[r3 + 1], x2 = x[r3 + 2];
      #pragma unroll
      for (int c = 0; c < 8; ++c) {
        const float s = fmaf(wv[c * 3 + 2], x2, fmaf(wv[c * 3 + 1], x1, wv[c * 3] * x0));
        acc[rr * 8 + c] = fmaxf(s + bv[c], 0.f);
      }
    }
  }
  ln64g(acc, P, lng, lnb, l, gr8, c0);
  storeA64g(A, acc, gr8, c0);
  __syncthreads();

  // ---- two hidden layers: 8 rows x 8 cols per lane, full k, W ping-pong ----
  #pragma unroll 1
  for (int layer = 0; layer < 2; ++layer) {
    const float* __restrict__ WT = layer == 0 ? wt1 : wt2;
    const float* __restrict__ Bp = layer == 0 ? bh : bh + 256;

    #define LDWQ(buf, kqv) { \
      _Pragma("unroll") \
      for (int kk_ = 0; kk_ < 4; ++kk_) { \
        buf[kk_ * 2]     = *(const float4*)&WT[(size_t)((kqv) * 4 + kk_) * 256 + c0]; \
        buf[kk_ * 2 + 1] = *(const float4*)&WT[(size_t)((kqv) * 4 + kk_) * 256 + c0 + 4]; \
      } }
    #define QUADF(kqv, wbuf) { \
      float4 a_[8]; \
      _Pragma("unroll") \
      for (int i_ = 0; i_ < 8; ++i_) a_[i_] = *(const float4*)&A[gr8 + i_][(kqv) * 4]; \
      _Pragma("unroll") \
      for (int kk_ = 0; kk_ < 4; ++kk_) { \
        const float4 wlo_ = wbuf[kk_ * 2], whi_ = wbuf[kk_ * 2 + 1]; \
        _Pragma("unroll") \
        for (int i_ = 0; i_ < 8; ++i_) { \
          const float av_ = kk_ == 0 ? a_[i_].x : kk_ == 1 ? a_[i_].y : kk_ == 2 ? a_[i_].z : a_[i_].w; \
          acc[i_ * 8 + 0] = fmaf(av_, wlo_.x, acc[i_ * 8 + 0]); \
          acc[i_ * 8 + 1] = fmaf(av_, wlo_.y, acc[i_ * 8 + 1]); \
          acc[i_ * 8 + 2] = fmaf(av_, wlo_.z, acc[i_ * 8 + 2]); \
          acc[i_ * 8 + 3] = fmaf(av_, wlo_.w, acc[i_ * 8 + 3]); \
          acc[i_ * 8 + 4] = fmaf(av_, whi_.x, acc[i_ * 8 + 4]); \
          acc[i_ * 8 + 5] = fmaf(av_, whi_.y, acc[i_ * 8 + 5]); \
          acc[i_ * 8 + 6] = fmaf(av_, whi_.z, acc[i_ * 8 + 6]); \
          acc[i_ * 8 + 7] = fmaf(av_, whi_.w, acc[i_ * 8 + 7]); \
        } } }

    #pragma unroll
    for (int i = 0; i < 64; ++i) acc[i] = 0.f;
    float4 wA[8], wB[8];
    LDWQ(wA, 0);
    #pragma unroll 1
    for (int kq = 0; kq < 64; kq += 2) {
      LDWQ(wB, kq + 1);
      QUADF(kq, wA);
      if (kq + 2 < 64) LDWQ(wA, kq + 2);
      QUADF(kq + 1, wB);
    }
    #undef LDWQ
    #undef QUADF
    { // bias + relu
      float bv[8];
      *(float4*)&bv[0] = *(const float4*)&Bp[c0];
      *(float4*)&bv[4] = *(const float4*)&Bp[c0 + 4];
      #pragma unroll
      for (int rr = 0; rr < 8; ++rr)
        #pragma unroll
        for (int c = 0; c < 8; ++c)
          acc[rr * 8 + c] = fmaxf(acc[rr * 8 + c] + bv[c], 0.f);
    }
    ln64g(acc, P, lng + 256 + layer * 256, lnb + 256 + layer * 256, l, gr8, c0);
    __syncthreads();              // all A-reads of this layer done (in-order wave; safety)
    storeA64g(A, acc, gr8, c0);
    __syncthreads();
  }

  { // out layer 256 -> 64: 8 rows x 2 cols per lane
    const int c0o = (l & 31) * 2;
    float o[16];
    #pragma unroll
    for (int i = 0; i < 16; ++i) o[i] = 0.f;
    #pragma unroll 1
    for (int kq = 0; kq < 64; ++kq) {
      float4 a[8];
      #pragma unroll
      for (int i = 0; i < 8; ++i) a[i] = *(const float4*)&A[gr8 + i][kq * 4];
      #pragma unroll
      for (int kk = 0; kk < 4; ++kk) {
        const float2 wv = *(const float2*)&wtout[(size_t)(kq * 4 + kk) * 64 + c0o];
        #pragma unroll
        for (int i = 0; i < 8; ++i) {
          const float av = kk == 0 ? a[i].x : kk == 1 ? a[i].y : kk == 2 ? a[i].z : a[i].w;
          o[i * 2]     = fmaf(av, wv.x, o[i * 2]);
          o[i * 2 + 1] = fmaf(av, wv.y, o[i * 2 + 1]);
        }
      }
    }
    const float2 bb = *(const float2*)&bout[c0o];
    #pragma unroll
    for (int rr = 0; rr < 8; ++rr) {
      float2 st;
      st.x = o[rr * 2] + bb.x;
      st.y = o[rr * 2 + 1] + bb.y;
      *(float2*)&z[(rbase + gr8 + rr) * 64 + c0o] = st;
    }
  }
}

// ---------------- weight transpose: WT[k][j] = W[j][k] ----------------
__global__ __launch_bounds__(256) void k_wt(const float* __restrict__ wh,
                                            const float* __restrict__ wout,
                                            float* __restrict__ wt1, float* __restrict__ wt2,
                                            float* __restrict__ wtout) {
  const int b = blockIdx.x, t = threadIdx.x;
  if (b < 256) {
    wt1[b * 256 + t] = wh[t * 256 + b];
  } else if (b < 512) {
    const int k = b - 256;
    wt2[k * 256 + t] = wh[65536 + t * 256 + k];
  } else {
    const int k = (b - 512) * 4 + (t >> 6);
    const int j = t & 63;
    wtout[k * 64 + j] = wout[j * 256 + k];
  }
}

// -------- decode table: table[512][3] = dec(codebook), ne[512] = ||e||^2 --------
__global__ __launch_bounds__(256) void k_table(
    const float* __restrict__ cb, const float* __restrict__ w0,
    const float* __restrict__ b0, const float* __restrict__ wh,
    const float* __restrict__ bh, const float* __restrict__ lng,
    const float* __restrict__ lnb, const float* __restrict__ wout,
    const float* __restrict__ bout, float* __restrict__ table,
    float* __restrict__ ne) {
  __shared__ float A[32][256];
  __shared__ float cs[32][64];
  const int t = threadIdx.x;
  const int cbase = blockIdx.x * 32;
  {
    float4* d = (float4*)&cs[0][0];
    const float4* s = (const float4*)(cb + cbase * 64);
    d[t] = s[t];
    d[t + 256] = s[t + 256];
  }
  __syncthreads();
  if (t < 32) {
    float s = 0.f;
    #pragma unroll 8
    for (int k = 0; k < 64; ++k) s = fmaf(cs[t][k], cs[t][k], s);
    ne[cbase + t] = s;
  }
  {
    const float4* Wr = (const float4*)(w0 + t * 64);
    float acc[32];
    #pragma unroll
    for (int r = 0; r < 32; ++r) acc[r] = 0.f;
    for (int kq = 0; kq < 16; ++kq) {
      const float4 w = Wr[kq];
      #pragma unroll
      for (int r = 0; r < 32; ++r) {
        const float4 a = *(const float4*)&cs[r][kq * 4];
        acc[r] = fma4(w, a, acc[r]);
      }
    }
    const float bb = b0[t];
    #pragma unroll
    for (int r = 0; r < 32; ++r) A[r][t] = fmaxf(acc[r] + bb, 0.f);
  }
  __syncthreads();
  ln_rows32(A, lng, lnb, t);
  hidden_layer32(A, wh, bh, t);
  ln_rows32(A, lng + 256, lnb + 256, t);
  hidden_layer32(A, wh + 65536, bh + 256, t);
  ln_rows32(A, lng + 512, lnb + 512, t);
  if (t < 96) {
    const int r = t / 3, j = t - r * 3;
    const float4* Wr = (const float4*)(wout + j * 256);
    float s = 0.f;
    #pragma unroll 4
    for (int kq = 0; kq < 64; ++kq) {
      const float4 w = Wr[kq];
      const float4 a = *(const float4*)&A[r][kq * 4];
      s = fma4(w, a, s);
    }
    table[(cbase + r) * 3 + j] = s + bout[j];
  }
}

// ---- VQ: z (in zq_io) -> argmin, quantized in-place, recon gather, partials ----
__global__ __launch_bounds__(256) void k_vq(
    float* __restrict__ zq_io, const float* __restrict__ cb,
    const float* __restrict__ ne, const float* __restrict__ table,
    const float* __restrict__ x, float* __restrict__ recon,
    float* __restrict__ psr, float* __restrict__ psv) {
  __shared__ float red[256];
  const int t = threadIdx.x;
  const int row = blockIdx.x * 256 + t;
  float4 zf[16];
  {
    const float4* zp = (const float4*)(zq_io + (size_t)row * 64);
    #pragma unroll
    for (int q = 0; q < 16; ++q) zf[q] = zp[q];
  }
  float nz = 0.f;
  #pragma unroll
  for (int q = 0; q < 16; ++q) {
    nz = fmaf(zf[q].x, zf[q].x, nz);
    nz = fmaf(zf[q].y, zf[q].y, nz);
    nz = fmaf(zf[q].z, zf[q].z, nz);
    nz = fmaf(zf[q].w, zf[q].w, nz);
  }
  float dmin = INFINITY; int imin = 0;
  const float4* cbv = (const float4*)cb;
  for (int c = 0; c < 512; ++c) {
    float da = 0.f, db = 0.f;
    #pragma unroll
    for (int q = 0; q < 16; q += 2) {
      const float4 ea = cbv[c * 16 + q];
      const float4 eb = cbv[c * 16 + q + 1];
      da = fmaf(ea.x, zf[q].x, da);
      da = fmaf(ea.y, zf[q].y, da);
      da = fmaf(ea.z, zf[q].z, da);
      da = fmaf(ea.w, zf[q].w, da);
      db = fmaf(eb.x, zf[q + 1].x, db);
      db = fmaf(eb.y, zf[q + 1].y, db);
      db = fmaf(eb.z, zf[q + 1].z, db);
      db = fmaf(eb.w, zf[q + 1].w, db);
    }
    const float dot = da + db;
    const float d = (nz + ne[c]) - 2.f * dot;
    if (d < dmin) { dmin = d; imin = c; }
  }
  float sv = 0.f;
  {
    const float4* eq = (const float4*)(cb + imin * 64);
    float4* qo = (float4*)(zq_io + (size_t)row * 64);
    #pragma unroll
    for (int q = 0; q < 16; ++q) {
      const float4 e = eq[q];
      const float4 zz = zf[q];
      const float ax = e.x - zz.x, ay = e.y - zz.y, az = e.z - zz.z, aw = e.w - zz.w;
      sv = fmaf(ax, ax, sv); sv = fmaf(ay, ay, sv);
      sv = fmaf(az, az, sv); sv = fmaf(aw, aw, sv);
      float4 st;
      st.x = zz.x + ax; st.y = zz.y + ay; st.z = zz.z + az; st.w = zz.w + aw;
      qo[q] = st;
    }
  }
  const float r0 = table[imin * 3], r1 = table[imin * 3 + 1], r2 = table[imin * 3 + 2];
  recon[row * 3] = r0; recon[row * 3 + 1] = r1; recon[row * 3 + 2] = r2;
  const float e0 = r0 - x[row * 3], e1 = r1 - x[row * 3 + 1], e2 = r2 - x[row * 3 + 2];
  const float sr = fmaf(e2, e2, fmaf(e1, e1, e0 * e0));
  red[t] = sr; __syncthreads();
  #pragma unroll
  for (int o = 128; o > 0; o >>= 1) { if (t < o) red[t] += red[t + o]; __syncthreads(); }
  if (t == 0) psr[blockIdx.x] = red[0];
  __syncthreads();
  red[t] = sv; __syncthreads();
  #pragma unroll
  for (int o = 128; o > 0; o >>= 1) { if (t < o) red[t] += red[t + o]; __syncthreads(); }
  if (t == 0) psv[blockIdx.x] = red[0];
}

// ---------------- final scalar loss ----------------
__global__ __launch_bounds__(256) void k_loss(
    const float* __restrict__ psr, const float* __restrict__ psv,
    float* __restrict__ out) {
  __shared__ float ra[256], rb[256];
  const int t = threadIdx.x;
  const float sr = ((psr[t] + psr[t + 256]) + psr[t + 512]) + psr[t + 768];
  const float sv = ((psv[t] + psv[t + 256]) + psv[t + 512]) + psv[t + 768];
  ra[t] = sr; rb[t] = sv;
  __syncthreads();
  #pragma unroll
  for (int o = 128; o > 0; o >>= 1) {
    if (t < o) { ra[t] += ra[t + o]; rb[t] += rb[t + o]; }
    __syncthreads();
  }
  if (t == 0) {
    const float mr = ra[0] / 786432.f;
    const float mv = rb[0] * (1.f / 16777216.f);
    const float vq = 0.25f * mv + mv;
    out[0] = mr + vq;
  }
}

extern "C" void kernel_launch(void* const* d_in, const int* in_sizes, int n_in,
                              void* d_out, int out_size, void* d_ws, size_t ws_size,
                              hipStream_t stream) {
  const float* x        = (const float*)d_in[0];
  const float* enc_w0   = (const float*)d_in[1];
  const float* enc_b0   = (const float*)d_in[2];
  const float* enc_wh   = (const float*)d_in[3];
  const float* enc_bh   = (const float*)d_in[4];
  const float* enc_lng  = (const float*)d_in[5];
  const float* enc_lnb  = (const float*)d_in[6];
  const float* enc_wout = (const float*)d_in[7];
  const float* enc_bout = (const float*)d_in[8];
  const float* cb       = (const float*)d_in[9];
  const float* dec_w0   = (const float*)d_in[10];
  const float* dec_b0   = (const float*)d_in[11];
  const float* dec_wh   = (const float*)d_in[12];
  const float* dec_bh   = (const float*)d_in[13];
  const float* dec_lng  = (const float*)d_in[14];
  const float* dec_lnb  = (const float*)d_in[15];
  const float* dec_wout = (const float*)d_in[16];
  const float* dec_bout = (const float*)d_in[17];

  float* out   = (float*)d_out;
  float* recon = out;                       // [N,3]
  float* qbuf  = out + 786432;              // [N,64]: z, then quantized in place
  float* lossp = out + 786432 + 16777216;   // scalar

  // Transposed weights live in the recon region (written before k_enc reads them,
  // fully overwritten by k_vq afterwards -> deterministic across replays).
  float* wt1   = out;                       // 65536
  float* wt2   = out + 65536;               // 65536
  float* wtout = out + 131072;              // 16384   (total 147456 < 786432)

  float* ws    = (float*)d_ws;
  float* ne    = ws;          // 512
  float* table = ws + 512;    // 512*3
  float* psr   = ws + 2048;   // 1024
  float* psv   = ws + 3072;   // 1024

  k_wt<<<576, 256, 0, stream>>>(enc_wh, enc_wout, wt1, wt2, wtout);
  k_table<<<16, 256, 0, stream>>>(cb, dec_w0, dec_b0, dec_wh, dec_bh,
                                  dec_lng, dec_lnb, dec_wout, dec_bout,
                                  table, ne);
  k_enc<<<16384, 64, 0, stream>>>(x, enc_w0, enc_b0, wt1, wt2, enc_bh,
                                  enc_lng, enc_lnb, wtout, enc_bout, qbuf);
  k_vq<<<1024, 256, 0, stream>>>(qbuf, cb, ne, table, x, recon, psr, psv);
  k_loss<<<1, 256, 0, stream>>>(psr, psv, lossp);
}